// Round 4
// baseline (1505.448 us; speedup 1.0000x reference)
//
#include <hip/hip_runtime.h>

// MonotoneiResBlock: B=131072 rows, D=64, H=256.
//   forward:  w <- sqrt2*x - tanh(w@W1)@W2   (10 iters; Lip~0.49)
//   y = sqrt2*w - x
//   logdet = -2 * eps . J(eps + J^2 e + J^4 e + J^6 e + J^8 e),  J v = (sech^2(w@W1) o (v@W1)) @ W2
// Transposed MFMA GEMMs, shared K-permutation pi so the D-frag of GEMM1 feeds GEMM2 as B-frag.
// Register discipline (round-3 spill was 2.4 GB of scratch traffic):
//   - GEMM2 interleaved into GEMM1: hbk is one transient u32x4, never an [8] array
//   - eps reloaded from HBM at the end instead of held across the Neumann loop
//   - named g0..g3 accumulators, template<MODE> passes, all-static indexing
//   - __launch_bounds__(512,4): 128-VGPR cap, 2 blocks/CU; peak live ~105 regs
// d_out FLOAT32: y = 131072*64, then logdet = 131072.

typedef __attribute__((ext_vector_type(8))) short bf16x8;
typedef __attribute__((ext_vector_type(4))) float f32x4;
typedef __attribute__((ext_vector_type(4))) unsigned int u32x4;

#define SQRT2F 1.41421356237309515f
#define NITER 10

__device__ __forceinline__ unsigned int pack2(float a, float b) {
    unsigned int ua = __builtin_bit_cast(unsigned int, a);
    unsigned int ub = __builtin_bit_cast(unsigned int, b);
    return ((ua + 0x8000u) >> 16) | ((ub + 0x8000u) & 0xFFFF0000u);
}
__device__ __forceinline__ float bf_lo(unsigned int u) { return __builtin_bit_cast(float, u << 16); }
__device__ __forceinline__ float bf_hi(unsigned int u) { return __builtin_bit_cast(float, u & 0xFFFF0000u); }
__device__ __forceinline__ float fast_tanh(float xx) {
    float a = __expf(xx + xx);
    float r = __builtin_amdgcn_rcpf(a + 1.0f);
    return fmaf(-2.0f, r, 1.0f);
}
__device__ __forceinline__ u32x4 packfrag(const float (&a)[4], const float (&b)[4]) {
    u32x4 r;
    r[0] = pack2(a[0], a[1]); r[1] = pack2(a[2], a[3]);
    r[2] = pack2(b[0], b[1]); r[3] = pack2(b[2], b[3]);
    return r;
}

// One fused pass: input B-frags bw0,bw1 (K=64 over D); GEMM1 tile m -> nonlinearity -> immediately
// fed to GEMM2 as B-frag k-step. MODE 0: tanh. MODE 1: tanh + capture dd (skip GEMM2). MODE 2: dd-mul.
template <int MODE>
__device__ __forceinline__ void fused_pass(const u32x4* __restrict__ sW1p, const u32x4* __restrict__ sW2p,
                                           int lane, bf16x8 bw0, bf16x8 bw1,
                                           unsigned int (&dpk)[16][2], float (&outv)[4][4]) {
    f32x4 zz = {0.f, 0.f, 0.f, 0.f};
    f32x4 g0 = zz, g1 = zz, g2 = zz, g3 = zz;
#pragma unroll
    for (int kk = 0; kk < 8; ++kk) {
        u32x4 hbk;
#pragma unroll
        for (int sub = 0; sub < 2; ++sub) {
            const int m = 2 * kk + sub;
            f32x4 acc = {0.f, 0.f, 0.f, 0.f};
            acc = __builtin_amdgcn_mfma_f32_16x16x32_bf16(
                __builtin_bit_cast(bf16x8, sW1p[(m * 2 + 0) * 64 + lane]), bw0, acc, 0, 0, 0);
            acc = __builtin_amdgcn_mfma_f32_16x16x32_bf16(
                __builtin_bit_cast(bf16x8, sW1p[(m * 2 + 1) * 64 + lane]), bw1, acc, 0, 0, 0);
            float h0, h1, h2, h3;
            if constexpr (MODE == 2) {
                h0 = acc[0] * bf_lo(dpk[m][0]);
                h1 = acc[1] * bf_hi(dpk[m][0]);
                h2 = acc[2] * bf_lo(dpk[m][1]);
                h3 = acc[3] * bf_hi(dpk[m][1]);
            } else {
                h0 = fast_tanh(acc[0]); h1 = fast_tanh(acc[1]);
                h2 = fast_tanh(acc[2]); h3 = fast_tanh(acc[3]);
                if constexpr (MODE == 1) {
                    dpk[m][0] = pack2(fmaf(-h0, h0, 1.0f), fmaf(-h1, h1, 1.0f));
                    dpk[m][1] = pack2(fmaf(-h2, h2, 1.0f), fmaf(-h3, h3, 1.0f));
                }
            }
            hbk[2 * sub + 0] = pack2(h0, h1);
            hbk[2 * sub + 1] = pack2(h2, h3);
        }
        if constexpr (MODE != 1) {
            bf16x8 bh = __builtin_bit_cast(bf16x8, hbk);
            g0 = __builtin_amdgcn_mfma_f32_16x16x32_bf16(
                __builtin_bit_cast(bf16x8, sW2p[(0 * 8 + kk) * 64 + lane]), bh, g0, 0, 0, 0);
            g1 = __builtin_amdgcn_mfma_f32_16x16x32_bf16(
                __builtin_bit_cast(bf16x8, sW2p[(1 * 8 + kk) * 64 + lane]), bh, g1, 0, 0, 0);
            g2 = __builtin_amdgcn_mfma_f32_16x16x32_bf16(
                __builtin_bit_cast(bf16x8, sW2p[(2 * 8 + kk) * 64 + lane]), bh, g2, 0, 0, 0);
            g3 = __builtin_amdgcn_mfma_f32_16x16x32_bf16(
                __builtin_bit_cast(bf16x8, sW2p[(3 * 8 + kk) * 64 + lane]), bh, g3, 0, 0, 0);
        }
    }
    if constexpr (MODE != 1) {
#pragma unroll
        for (int r = 0; r < 4; ++r) {
            outv[0][r] = g0[r]; outv[1][r] = g1[r]; outv[2][r] = g2[r]; outv[3][r] = g3[r];
        }
    }
}

__global__ __launch_bounds__(512, 4) void monot_kernel(
    const float* __restrict__ x, const float* __restrict__ eps,
    const float* __restrict__ W1, const float* __restrict__ W2,
    float* __restrict__ out) {
    __shared__ u32x4 sW1p[2048];  // [m0(16)][kk(2)][lane(64)] A-frags of W1^T, pi-permuted K
    __shared__ u32x4 sW2p[2048];  // [m0(4)][kk(8)][lane(64)]  A-frags of W2^T

    const int tid = threadIdx.x;
    const int lane = tid & 63;
    const int wv = tid >> 6;
    const int c = lane & 15;
    const int q = lane >> 4;

    // ---- pack weights into LDS (A-frag layout; pi(q,j) = 4q + (j&3) + 16*(j>>2)) ----
#pragma unroll
    for (int e0 = 0; e0 < 4; ++e0) {
        int idx = e0 * 512 + tid;  // W1 entries
        int l = idx & 63;
        int lq = l >> 4, lc = l & 15;
        int m0 = idx >> 7;
        int kk = (idx >> 6) & 1;
        float v[8];
#pragma unroll
        for (int j = 0; j < 8; ++j) {
            int kp = 32 * kk + 4 * lq + (j & 3) + ((j >> 2) << 4);
            v[j] = W1[kp * 256 + 16 * m0 + lc];  // W1^T[16m0+lc][kp]
        }
        u32x4 pk;
        pk[0] = pack2(v[0], v[1]); pk[1] = pack2(v[2], v[3]);
        pk[2] = pack2(v[4], v[5]); pk[3] = pack2(v[6], v[7]);
        sW1p[idx] = pk;
    }
#pragma unroll
    for (int e0 = 0; e0 < 4; ++e0) {
        int idx = e0 * 512 + tid;  // W2 entries
        int l = idx & 63;
        int lq = l >> 4, lc = l & 15;
        int m0 = idx >> 9;
        int kk = (idx >> 6) & 7;
        float v[8];
#pragma unroll
        for (int j = 0; j < 8; ++j) {
            int kp = 32 * kk + 4 * lq + (j & 3) + ((j >> 2) << 4);
            v[j] = W2[kp * 64 + 16 * m0 + lc];  // W2^T[16m0+lc][kp]
        }
        u32x4 pk;
        pk[0] = pack2(v[0], v[1]); pk[1] = pack2(v[2], v[3]);
        pk[2] = pack2(v[4], v[5]); pk[3] = pack2(v[6], v[7]);
        sW2p[idx] = pk;
    }
    __syncthreads();

    const int row = blockIdx.x * 128 + wv * 16 + c;
    const float* xr = x + (size_t)row * 64;

    unsigned int dpk[16][2];  // dd packed bf16 (filled by MODE-1 pass)

    // lane holds dims d = 16*m + 4*q + r of its row
    float xw[4][4], w[4][4];
#pragma unroll
    for (int m = 0; m < 4; ++m) {
        f32x4 t = *(const f32x4*)(xr + 16 * m + 4 * q);
#pragma unroll
        for (int r = 0; r < 4; ++r) { xw[m][r] = t[r]; w[m][r] = SQRT2F * t[r]; }
    }

    // ---- fixed-point iterations ----
#pragma unroll 1
    for (int it = 0; it < NITER; ++it) {
        bf16x8 bw0 = __builtin_bit_cast(bf16x8, packfrag(w[0], w[1]));
        bf16x8 bw1 = __builtin_bit_cast(bf16x8, packfrag(w[2], w[3]));
        float gout[4][4];
        fused_pass<0>(sW1p, sW2p, lane, bw0, bw1, dpk, gout);
#pragma unroll
        for (int m = 0; m < 4; ++m)
#pragma unroll
            for (int r = 0; r < 4; ++r) w[m][r] = fmaf(SQRT2F, xw[m][r], -gout[m][r]);
    }

    // ---- y = sqrt2*w - x ----
#pragma unroll
    for (int m = 0; m < 4; ++m) {
        f32x4 st;
#pragma unroll
        for (int r = 0; r < 4; ++r) st[r] = fmaf(SQRT2F, w[m][r], -xw[m][r]);
        *(f32x4*)(out + (size_t)row * 64 + 16 * m + 4 * q) = st;
    }

    // ---- dd = sech^2(w@W1) at converged w (GEMM1 only) ----
    {
        bf16x8 bw0 = __builtin_bit_cast(bf16x8, packfrag(w[0], w[1]));
        bf16x8 bw1 = __builtin_bit_cast(bf16x8, packfrag(w[2], w[3]));
        float dummy[4][4];
        fused_pass<1>(sW1p, sW2p, lane, bw0, bw1, dpk, dummy);
    }

    // ---- Neumann: s = e + J^2 e + J^4 e + J^6 e + J^8 e; logdet = -2 eps.(J s) ----
    float s[4][4], v[4][4];
    {
        const float* er = eps + (size_t)row * 64;
#pragma unroll
        for (int m = 0; m < 4; ++m) {
            f32x4 t = *(const f32x4*)(er + 16 * m + 4 * q);
#pragma unroll
            for (int r = 0; r < 4; ++r) { s[m][r] = t[r]; v[m][r] = t[r]; }
        }
    }
#pragma unroll 1
    for (int k = 1; k <= 8; ++k) {
        bf16x8 b0 = __builtin_bit_cast(bf16x8, packfrag(v[0], v[1]));
        bf16x8 b1 = __builtin_bit_cast(bf16x8, packfrag(v[2], v[3]));
        fused_pass<2>(sW1p, sW2p, lane, b0, b1, dpk, v);
        if ((k & 1) == 0) {
#pragma unroll
            for (int m = 0; m < 4; ++m)
#pragma unroll
                for (int r = 0; r < 4; ++r) s[m][r] += v[m][r];
        }
    }
    float tt[4][4];
    {
        bf16x8 b0 = __builtin_bit_cast(bf16x8, packfrag(s[0], s[1]));
        bf16x8 b1 = __builtin_bit_cast(bf16x8, packfrag(s[2], s[3]));
        fused_pass<2>(sW1p, sW2p, lane, b0, b1, dpk, tt);
    }
    // reload eps for the final dot (keeps it out of the loop's live set)
    float p = 0.f;
    {
        const float* er = eps + (size_t)row * 64;
#pragma unroll
        for (int m = 0; m < 4; ++m) {
            f32x4 t = *(const f32x4*)(er + 16 * m + 4 * q);
#pragma unroll
            for (int r = 0; r < 4; ++r) p = fmaf(t[r], tt[m][r], p);
        }
    }
    p += __shfl_xor(p, 16);
    p += __shfl_xor(p, 32);
    p *= -2.0f;
    if (lane < 16) out[(size_t)8388608 + row] = p;
}

extern "C" void kernel_launch(void* const* d_in, const int* in_sizes, int n_in,
                              void* d_out, int out_size, void* d_ws, size_t ws_size,
                              hipStream_t stream) {
    const float* x = (const float*)d_in[0];
    const float* eps = (const float*)d_in[1];
    const float* W1 = (const float*)d_in[2];
    const float* W2 = (const float*)d_in[3];
    float* out = (float*)d_out;
    monot_kernel<<<dim3(1024), dim3(512), 0, stream>>>(x, eps, W1, W2, out);
}

// Round 5
// 672.404 us; speedup vs baseline: 2.2389x; 2.2389x over previous
//
#include <hip/hip_runtime.h>

// MonotoneiResBlock: B=131072 rows, D=64, H=256.
//   forward:  w <- sqrt2*x - tanh(w@W1)@W2   (10 iters; Lip~0.49)
//   y = sqrt2*w - x
//   logdet = -2 * eps . J(eps + J^2 e + J^4 e + J^6 e + J^8 e),  J v = (sech^2(w@W1) o (v@W1)) @ W2
// Transposed MFMA GEMMs, shared K-permutation pi so GEMM1's D-frag feeds GEMM2 as B-frag.
// Round-5 changes:
//   - __launch_bounds__(512,1): hipcc uses CUDA min-BLOCKS semantics (round-4 evidence: (512,4)->64 VGPR).
//     (512,1) -> 256-VGPR cap -> no scratch spill (rounds 2-4 were all spill-bound: 2-4 GB phantom HBM).
//   - 32 rows/wave (two 16-row B-frag groups share every weight A-frag ds_read): halves LDS traffic/row.
// d_out FLOAT32: y = 131072*64, then logdet = 131072.

typedef __attribute__((ext_vector_type(8))) short bf16x8;
typedef __attribute__((ext_vector_type(4))) float f32x4;
typedef __attribute__((ext_vector_type(4))) unsigned int u32x4;

#define SQRT2F 1.41421356237309515f
#define NITER 10

__device__ __forceinline__ unsigned int pack2(float a, float b) {
    unsigned int ua = __builtin_bit_cast(unsigned int, a);
    unsigned int ub = __builtin_bit_cast(unsigned int, b);
    return ((ua + 0x8000u) >> 16) | ((ub + 0x8000u) & 0xFFFF0000u);
}
__device__ __forceinline__ float bf_lo(unsigned int u) { return __builtin_bit_cast(float, u << 16); }
__device__ __forceinline__ float bf_hi(unsigned int u) { return __builtin_bit_cast(float, u & 0xFFFF0000u); }
__device__ __forceinline__ float fast_tanh(float xx) {
    float a = __expf(xx + xx);
    float r = __builtin_amdgcn_rcpf(a + 1.0f);
    return fmaf(-2.0f, r, 1.0f);
}
__device__ __forceinline__ u32x4 packfrag(const float (&a)[4], const float (&b)[4]) {
    u32x4 r;
    r[0] = pack2(a[0], a[1]); r[1] = pack2(a[2], a[3]);
    r[2] = pack2(b[0], b[1]); r[3] = pack2(b[2], b[3]);
    return r;
}

// Fused pass over 32 rows (groups 0,1 of 16 rows). Weight A-frags loaded ONCE, used by both groups.
// MODE 0: tanh. MODE 1: tanh + capture dd, skip GEMM2. MODE 2: dd-multiply.
template <int MODE>
__device__ __forceinline__ void fused_pass32(const u32x4* __restrict__ sW1p, const u32x4* __restrict__ sW2p,
                                             int lane, bf16x8 b00, bf16x8 b01, bf16x8 b10, bf16x8 b11,
                                             unsigned int (&dpk)[2][16][2], float (&outv)[2][4][4]) {
    f32x4 zz = {0.f, 0.f, 0.f, 0.f};
    f32x4 g[2][4];
#pragma unroll
    for (int gi = 0; gi < 2; ++gi)
#pragma unroll
        for (int t = 0; t < 4; ++t) g[gi][t] = zz;
#pragma unroll
    for (int kk = 0; kk < 8; ++kk) {
        u32x4 hbk0, hbk1;
#pragma unroll
        for (int sub = 0; sub < 2; ++sub) {
            const int m = 2 * kk + sub;
            u32x4 wA = sW1p[(m * 2 + 0) * 64 + lane];
            u32x4 wB = sW1p[(m * 2 + 1) * 64 + lane];
            f32x4 a0 = zz, a1 = zz;
            a0 = __builtin_amdgcn_mfma_f32_16x16x32_bf16(__builtin_bit_cast(bf16x8, wA), b00, a0, 0, 0, 0);
            a0 = __builtin_amdgcn_mfma_f32_16x16x32_bf16(__builtin_bit_cast(bf16x8, wB), b01, a0, 0, 0, 0);
            a1 = __builtin_amdgcn_mfma_f32_16x16x32_bf16(__builtin_bit_cast(bf16x8, wA), b10, a1, 0, 0, 0);
            a1 = __builtin_amdgcn_mfma_f32_16x16x32_bf16(__builtin_bit_cast(bf16x8, wB), b11, a1, 0, 0, 0);
            float h00, h01, h02, h03, h10, h11, h12, h13;
            if constexpr (MODE == 2) {
                h00 = a0[0] * bf_lo(dpk[0][m][0]);
                h01 = a0[1] * bf_hi(dpk[0][m][0]);
                h02 = a0[2] * bf_lo(dpk[0][m][1]);
                h03 = a0[3] * bf_hi(dpk[0][m][1]);
                h10 = a1[0] * bf_lo(dpk[1][m][0]);
                h11 = a1[1] * bf_hi(dpk[1][m][0]);
                h12 = a1[2] * bf_lo(dpk[1][m][1]);
                h13 = a1[3] * bf_hi(dpk[1][m][1]);
            } else {
                h00 = fast_tanh(a0[0]); h01 = fast_tanh(a0[1]);
                h02 = fast_tanh(a0[2]); h03 = fast_tanh(a0[3]);
                h10 = fast_tanh(a1[0]); h11 = fast_tanh(a1[1]);
                h12 = fast_tanh(a1[2]); h13 = fast_tanh(a1[3]);
                if constexpr (MODE == 1) {
                    dpk[0][m][0] = pack2(fmaf(-h00, h00, 1.0f), fmaf(-h01, h01, 1.0f));
                    dpk[0][m][1] = pack2(fmaf(-h02, h02, 1.0f), fmaf(-h03, h03, 1.0f));
                    dpk[1][m][0] = pack2(fmaf(-h10, h10, 1.0f), fmaf(-h11, h11, 1.0f));
                    dpk[1][m][1] = pack2(fmaf(-h12, h12, 1.0f), fmaf(-h13, h13, 1.0f));
                }
            }
            hbk0[2 * sub + 0] = pack2(h00, h01); hbk0[2 * sub + 1] = pack2(h02, h03);
            hbk1[2 * sub + 0] = pack2(h10, h11); hbk1[2 * sub + 1] = pack2(h12, h13);
        }
        if constexpr (MODE != 1) {
            bf16x8 bh0 = __builtin_bit_cast(bf16x8, hbk0);
            bf16x8 bh1 = __builtin_bit_cast(bf16x8, hbk1);
#pragma unroll
            for (int t = 0; t < 4; ++t) {
                bf16x8 w2 = __builtin_bit_cast(bf16x8, sW2p[(t * 8 + kk) * 64 + lane]);
                g[0][t] = __builtin_amdgcn_mfma_f32_16x16x32_bf16(w2, bh0, g[0][t], 0, 0, 0);
                g[1][t] = __builtin_amdgcn_mfma_f32_16x16x32_bf16(w2, bh1, g[1][t], 0, 0, 0);
            }
        }
    }
    if constexpr (MODE != 1) {
#pragma unroll
        for (int gi = 0; gi < 2; ++gi)
#pragma unroll
            for (int t = 0; t < 4; ++t)
#pragma unroll
                for (int r = 0; r < 4; ++r) outv[gi][t][r] = g[gi][t][r];
    }
}

__global__ __launch_bounds__(512, 1) void monot_kernel(
    const float* __restrict__ x, const float* __restrict__ eps,
    const float* __restrict__ W1, const float* __restrict__ W2,
    float* __restrict__ out) {
    __shared__ u32x4 sW1p[2048];  // [m0(16)][kk(2)][lane(64)] A-frags of W1^T, pi-permuted K
    __shared__ u32x4 sW2p[2048];  // [m0(4)][kk(8)][lane(64)]  A-frags of W2^T

    const int tid = threadIdx.x;
    const int lane = tid & 63;
    const int wv = tid >> 6;
    const int c = lane & 15;
    const int q = lane >> 4;

    // ---- pack weights into LDS (A-frag layout; pi(q,j) = 4q + (j&3) + 16*(j>>2)) ----
#pragma unroll
    for (int e0 = 0; e0 < 4; ++e0) {
        int idx = e0 * 512 + tid;  // W1 entries
        int l = idx & 63;
        int lq = l >> 4, lc = l & 15;
        int m0 = idx >> 7;
        int kk = (idx >> 6) & 1;
        float v[8];
#pragma unroll
        for (int j = 0; j < 8; ++j) {
            int kp = 32 * kk + 4 * lq + (j & 3) + ((j >> 2) << 4);
            v[j] = W1[kp * 256 + 16 * m0 + lc];  // W1^T[16m0+lc][kp]
        }
        u32x4 pk;
        pk[0] = pack2(v[0], v[1]); pk[1] = pack2(v[2], v[3]);
        pk[2] = pack2(v[4], v[5]); pk[3] = pack2(v[6], v[7]);
        sW1p[idx] = pk;
    }
#pragma unroll
    for (int e0 = 0; e0 < 4; ++e0) {
        int idx = e0 * 512 + tid;  // W2 entries
        int l = idx & 63;
        int lq = l >> 4, lc = l & 15;
        int m0 = idx >> 9;
        int kk = (idx >> 6) & 7;
        float v[8];
#pragma unroll
        for (int j = 0; j < 8; ++j) {
            int kp = 32 * kk + 4 * lq + (j & 3) + ((j >> 2) << 4);
            v[j] = W2[kp * 64 + 16 * m0 + lc];  // W2^T[16m0+lc][kp]
        }
        u32x4 pk;
        pk[0] = pack2(v[0], v[1]); pk[1] = pack2(v[2], v[3]);
        pk[2] = pack2(v[4], v[5]); pk[3] = pack2(v[6], v[7]);
        sW2p[idx] = pk;
    }
    __syncthreads();

    // wave handles 32 rows: group0 = row0..row0+15 (lane c), group1 = +16
    const int row0 = blockIdx.x * 256 + wv * 32 + c;
    const float* xr0 = x + (size_t)row0 * 64;
    const float* xr1 = xr0 + 16 * 64;

    unsigned int dpk[2][16][2];  // dd packed bf16 per group

    float xw[2][4][4], w[2][4][4];
#pragma unroll
    for (int m = 0; m < 4; ++m) {
        f32x4 t0 = *(const f32x4*)(xr0 + 16 * m + 4 * q);
        f32x4 t1 = *(const f32x4*)(xr1 + 16 * m + 4 * q);
#pragma unroll
        for (int r = 0; r < 4; ++r) {
            xw[0][m][r] = t0[r]; w[0][m][r] = SQRT2F * t0[r];
            xw[1][m][r] = t1[r]; w[1][m][r] = SQRT2F * t1[r];
        }
    }

    // ---- fixed-point iterations ----
#pragma unroll 1
    for (int it = 0; it < NITER; ++it) {
        bf16x8 b00 = __builtin_bit_cast(bf16x8, packfrag(w[0][0], w[0][1]));
        bf16x8 b01 = __builtin_bit_cast(bf16x8, packfrag(w[0][2], w[0][3]));
        bf16x8 b10 = __builtin_bit_cast(bf16x8, packfrag(w[1][0], w[1][1]));
        bf16x8 b11 = __builtin_bit_cast(bf16x8, packfrag(w[1][2], w[1][3]));
        float gout[2][4][4];
        fused_pass32<0>(sW1p, sW2p, lane, b00, b01, b10, b11, dpk, gout);
#pragma unroll
        for (int gi = 0; gi < 2; ++gi)
#pragma unroll
            for (int m = 0; m < 4; ++m)
#pragma unroll
                for (int r = 0; r < 4; ++r) w[gi][m][r] = fmaf(SQRT2F, xw[gi][m][r], -gout[gi][m][r]);
    }

    // ---- y = sqrt2*w - x ----
#pragma unroll
    for (int m = 0; m < 4; ++m) {
        f32x4 s0, s1;
#pragma unroll
        for (int r = 0; r < 4; ++r) {
            s0[r] = fmaf(SQRT2F, w[0][m][r], -xw[0][m][r]);
            s1[r] = fmaf(SQRT2F, w[1][m][r], -xw[1][m][r]);
        }
        *(f32x4*)(out + (size_t)row0 * 64 + 16 * m + 4 * q) = s0;
        *(f32x4*)(out + (size_t)(row0 + 16) * 64 + 16 * m + 4 * q) = s1;
    }

    // ---- dd = sech^2(w@W1) at converged w ----
    {
        bf16x8 b00 = __builtin_bit_cast(bf16x8, packfrag(w[0][0], w[0][1]));
        bf16x8 b01 = __builtin_bit_cast(bf16x8, packfrag(w[0][2], w[0][3]));
        bf16x8 b10 = __builtin_bit_cast(bf16x8, packfrag(w[1][0], w[1][1]));
        bf16x8 b11 = __builtin_bit_cast(bf16x8, packfrag(w[1][2], w[1][3]));
        float dummy[2][4][4];
        fused_pass32<1>(sW1p, sW2p, lane, b00, b01, b10, b11, dpk, dummy);
    }

    // ---- Neumann: s = e + J^2 e + J^4 e + J^6 e + J^8 e; logdet = -2 eps.(J s) ----
    float s[2][4][4], v[2][4][4];
    {
        const float* er0 = eps + (size_t)row0 * 64;
        const float* er1 = er0 + 16 * 64;
#pragma unroll
        for (int m = 0; m < 4; ++m) {
            f32x4 t0 = *(const f32x4*)(er0 + 16 * m + 4 * q);
            f32x4 t1 = *(const f32x4*)(er1 + 16 * m + 4 * q);
#pragma unroll
            for (int r = 0; r < 4; ++r) {
                s[0][m][r] = t0[r]; v[0][m][r] = t0[r];
                s[1][m][r] = t1[r]; v[1][m][r] = t1[r];
            }
        }
    }
#pragma unroll 1
    for (int k = 1; k <= 8; ++k) {
        bf16x8 b00 = __builtin_bit_cast(bf16x8, packfrag(v[0][0], v[0][1]));
        bf16x8 b01 = __builtin_bit_cast(bf16x8, packfrag(v[0][2], v[0][3]));
        bf16x8 b10 = __builtin_bit_cast(bf16x8, packfrag(v[1][0], v[1][1]));
        bf16x8 b11 = __builtin_bit_cast(bf16x8, packfrag(v[1][2], v[1][3]));
        fused_pass32<2>(sW1p, sW2p, lane, b00, b01, b10, b11, dpk, v);
        if ((k & 1) == 0) {
#pragma unroll
            for (int gi = 0; gi < 2; ++gi)
#pragma unroll
                for (int m = 0; m < 4; ++m)
#pragma unroll
                    for (int r = 0; r < 4; ++r) s[gi][m][r] += v[gi][m][r];
        }
    }
    float tt[2][4][4];
    {
        bf16x8 b00 = __builtin_bit_cast(bf16x8, packfrag(s[0][0], s[0][1]));
        bf16x8 b01 = __builtin_bit_cast(bf16x8, packfrag(s[0][2], s[0][3]));
        bf16x8 b10 = __builtin_bit_cast(bf16x8, packfrag(s[1][0], s[1][1]));
        bf16x8 b11 = __builtin_bit_cast(bf16x8, packfrag(s[1][2], s[1][3]));
        fused_pass32<2>(sW1p, sW2p, lane, b00, b01, b10, b11, dpk, tt);
    }
    // reload eps for the final dot
    float p0 = 0.f, p1 = 0.f;
    {
        const float* er0 = eps + (size_t)row0 * 64;
        const float* er1 = er0 + 16 * 64;
#pragma unroll
        for (int m = 0; m < 4; ++m) {
            f32x4 t0 = *(const f32x4*)(er0 + 16 * m + 4 * q);
            f32x4 t1 = *(const f32x4*)(er1 + 16 * m + 4 * q);
#pragma unroll
            for (int r = 0; r < 4; ++r) {
                p0 = fmaf(t0[r], tt[0][m][r], p0);
                p1 = fmaf(t1[r], tt[1][m][r], p1);
            }
        }
    }
    p0 += __shfl_xor(p0, 16); p0 += __shfl_xor(p0, 32);
    p1 += __shfl_xor(p1, 16); p1 += __shfl_xor(p1, 32);
    p0 *= -2.0f; p1 *= -2.0f;
    if (lane < 16) {
        out[(size_t)8388608 + row0] = p0;
        out[(size_t)8388608 + row0 + 16] = p1;
    }
}

extern "C" void kernel_launch(void* const* d_in, const int* in_sizes, int n_in,
                              void* d_out, int out_size, void* d_ws, size_t ws_size,
                              hipStream_t stream) {
    const float* x = (const float*)d_in[0];
    const float* eps = (const float*)d_in[1];
    const float* W1 = (const float*)d_in[2];
    const float* W2 = (const float*)d_in[3];
    float* out = (float*)d_out;
    // 131072 rows / (8 waves * 32 rows) = 512 blocks
    monot_kernel<<<dim3(512), dim3(512), 0, stream>>>(x, eps, W1, W2, out);
}